// Round 12
// baseline (161.688 us; speedup 1.0000x reference)
//
#include <hip/hip_runtime.h>
#include <stdint.h>

#define N_NODES 50000
#define N_EDGES 1600000
#define N_FEAT 128
#define CAP 64            // final slots per row; Poisson(28.8) mean, +6.5 sigma
#define OVF_PW 256        // per-convA-wg overflow slots (expected usage: ~0)
#define OVF_PB 128        // per-bucket overflow slots (expected usage: ~0)

// radix-partition parameters (round 12: 64-row buckets -> 782 wgs, ~3 wgs/CU
// co-resident so one wg's rank prologue hides under others' gather loads)
#define RSHIFT 6          // 64 rows per bucket
#define BROWS 64
#define NB 782            // ceil(50000 / 64)
#define NWG_A 250         // pass-A workgroups; 250*1600 chunks * 4 edges = 1.6M exact
#define A_THREADS 1024
#define CHUNKS_PW 1600    // 4-edge chunks per pass-A wg
#define CAPW 24           // slots per (bucket, wg) segment; mean 7.35, +6.1 sigma
#define NREG (NWG_A + NB) // 1032 overflow regions total

// ---------------- threefry2x32 (bit-exact, KAT-verified vs Random123) ----------

struct KeyPair { uint32_t a, b; };

__host__ __device__ constexpr inline uint32_t rotl32(uint32_t x, int r) {
  return (x << r) | (x >> (32 - r));
}

__host__ __device__ constexpr inline KeyPair threefry2x32(uint32_t k0, uint32_t k1,
                                                          uint32_t x0, uint32_t x1) {
  const uint32_t ks0 = k0, ks1 = k1, ks2 = k0 ^ k1 ^ 0x1BD11BDAu;
  x0 += ks0;
  x1 += ks1;
  const int rotA[4] = {13, 15, 26, 6};
  const int rotB[4] = {17, 29, 16, 24};
  const uint32_t ks[3] = {ks0, ks1, ks2};
  for (int i = 0; i < 5; ++i) {
    const int* rot = (i & 1) ? rotB : rotA;
    for (int j = 0; j < 4; ++j) {
      x0 += x1;
      x1 = rotl32(x1, rot[j]);
      x1 ^= x0;
    }
    x0 += ks[(i + 1) % 3];
    x1 += ks[(i + 2) % 3] + (uint32_t)(i + 1);
  }
  return {x0, x1};
}

// mask_key = fold_in(key(42), 7); compile-time.
constexpr KeyPair MASK_KEY = threefry2x32(0u, 42u, 0u, 7u);

// Partitionable (counter-mode) random_bits: element i -> threefry(key, (0, i)), bits = b1^b2.
__device__ inline bool edge_keep(uint32_t e) {
  KeyPair r = threefry2x32(MASK_KEY.a, MASK_KEY.b, 0u, e);
  uint32_t bits = r.a ^ r.b;
  float u = __uint_as_float((bits >> 9) | 0x3f800000u) - 1.0f;
  return u < 0.9f;
}

// fp32 bits -> bf16 with round-to-nearest-even
__device__ inline uint32_t f2bf(uint32_t b) {
  return (b + 0x7fffu + ((b >> 16) & 1u)) >> 16;
}

// true vector types (ext_vector_type) -- __builtin_nontemporal_* rejects HIP's
// class-type uint2/float4, but accepts these (identical layout & codegen).
typedef uint32_t u4v __attribute__((ext_vector_type(4)));
typedef int32_t  i4v __attribute__((ext_vector_type(4)));
typedef float    f4v __attribute__((ext_vector_type(4)));

// =================== PRIMARY PATH ==============================================
// coarse pack (8B u64, r11's 5B split REVERTED -- it cost +6us: extra store and
// load streams + FETCH +5MB): (row << 48) | (col << 32) | f32bits(val).
// wg-major layout: coarse[(wg*NB + b)*CAPW + li] (r8: private per-wg window).
// Post-mortems baked in: no global atomics (r2), cached producer->consumer
// stores / NT for read-once streams (r4), eager preloads (r5), fused conversion
// (r7), LDS payload in merged rank+gather (r9, -8us), rank preload rounds (r10,
// -4us), +rl pay swizzle (r11, conflict fix, timing-neutral but free).

// Pass A (fused with x->bf16 conversion): per-wg compaction into (bucket, wg)
// segments using LDS counters only. One barrier, before phase 0 (r11 placement:
// no phase0->phase1 straggler coupling). Edge arrays + x read-once -> NT loads.
// Per-wg overflow count written unconditionally -> no memset dispatch.
__global__ void __launch_bounds__(A_THREADS) convA_kernel(const float* __restrict__ x,
                                                          uint32_t* __restrict__ xb,
                                                          const float* __restrict__ adj_vals,
                                                          const int* __restrict__ row,
                                                          const int* __restrict__ col,
                                                          uint64_t* __restrict__ coarse,
                                                          uint32_t* __restrict__ lens,
                                                          uint32_t* __restrict__ ovfcA,
                                                          uint64_t* __restrict__ ovfA) {
  __shared__ uint32_t cnt[NB];
  __shared__ uint32_t ovfc;
  int wg = blockIdx.x;
  int tid = threadIdx.x;
  if (tid < NB) cnt[tid] = 0;
  if (tid == 0) ovfc = 0;
  __syncthreads();  // cnt/ovfc init visible to phase-1 atomics (only barrier)

  // phase 0: x -> bf16, 32B in / 16B out per iteration (NT in, cached out)
  const int gthreads = NWG_A * A_THREADS;
  for (int i = wg * A_THREADS + tid; i < (N_NODES * N_FEAT) / 8; i += gthreads) {
    f4v a = __builtin_nontemporal_load((const f4v*)x + 2 * i);
    f4v b = __builtin_nontemporal_load((const f4v*)x + 2 * i + 1);
    u4v o;
    o.x = f2bf(__float_as_uint(a.x)) | (f2bf(__float_as_uint(a.y)) << 16);
    o.y = f2bf(__float_as_uint(a.z)) | (f2bf(__float_as_uint(a.w)) << 16);
    o.z = f2bf(__float_as_uint(b.x)) | (f2bf(__float_as_uint(b.y)) << 16);
    o.w = f2bf(__float_as_uint(b.z)) | (f2bf(__float_as_uint(b.w)) << 16);
    ((u4v*)xb)[i] = o;
  }

  // phase 1: bin 4-edge chunks (NT vector loads), LDS-atomic slot ranks,
  // wg-major coarse scatter (private ~150KB window, mostly L2-resident)
  uint64_t* my_coarse = coarse + (size_t)wg * NB * CAPW;
  for (int ch = tid; ch < CHUNKS_PW; ch += A_THREADS) {
    const int g = wg * CHUNKS_PW + ch;     // global chunk; edges [4g, 4g+4)
    const i4v r4 = __builtin_nontemporal_load((const i4v*)row + g);
    const i4v c4 = __builtin_nontemporal_load((const i4v*)col + g);
    const f4v a4 = __builtin_nontemporal_load((const f4v*)adj_vals + g);
    const int rr[4] = {r4.x, r4.y, r4.z, r4.w};
    const int cc[4] = {c4.x, c4.y, c4.z, c4.w};
    const float aa[4] = {a4.x, a4.y, a4.z, a4.w};
#pragma unroll
    for (int k = 0; k < 4; ++k) {
      const uint32_t e = (uint32_t)(4 * g + k);
      if (!edge_keep(e)) continue;
      const uint32_t r = (uint32_t)rr[k];
      const uint32_t c = (uint32_t)cc[k];
      const float v = aa[k] / 0.9f;
      const uint32_t b = r >> RSHIFT;
      const uint32_t li = atomicAdd(&cnt[b], 1u);
      const uint64_t p = ((uint64_t)r << 48) | ((uint64_t)c << 32) | (uint64_t)__float_as_uint(v);
      if (li < CAPW) {
        my_coarse[(size_t)b * CAPW + li] = p;
      } else {
        const uint32_t oi = atomicAdd(&ovfc, 1u);
        if (oi < OVF_PW) ovfA[(size_t)wg * OVF_PW + oi] = p;
      }
    }
  }
  __syncthreads();
  if (tid < NB) lens[(size_t)tid * NWG_A + wg] = min(cnt[tid], (uint32_t)CAPW);
  if (tid == 0) ovfcA[wg] = min(ovfc, (uint32_t)OVF_PW);
}

// Merged rank + gather: one 256-thread wg per 64-row bucket (782 wgs -> ~3
// wgs/CU co-resident; ~17.5KB LDS). Rank: SINGLE unconditional preload round
// (slot `lane` of all 16 segments per team -- 16 independent NT loads in
// flight; mean len 7.35 so P(len>16)=0.07% -> rare tail loop). One dependent
// load round instead of r10's two. +rl pay swizzle (bank = (idx+rl)&31).
__global__ void __launch_bounds__(256) rank_gather_kernel(const uint32_t* __restrict__ xb,
                                                          const uint64_t* __restrict__ coarse,
                                                          const uint32_t* __restrict__ lens,
                                                          uint32_t* __restrict__ ovfcB,
                                                          uint64_t* __restrict__ ovfB,
                                                          float* __restrict__ out) {
  int b = blockIdx.x;
  int tid = threadIdx.x;
  __shared__ uint32_t pay[BROWS * CAP];   // 16 KB payload tile
  __shared__ uint32_t cnt[BROWS];
  __shared__ uint32_t s_len[NWG_A];
  __shared__ uint32_t ovfc;
  for (int i = tid; i < BROWS * CAP; i += 256) pay[i] = 0u;
  if (tid < BROWS) cnt[tid] = 0;
  if (tid < NWG_A) s_len[tid] = lens[(size_t)b * NWG_A + tid];
  if (tid == 0) ovfc = 0;
  __syncthreads();

  int team = tid >> 4;        // 16 teams of 16 lanes
  int lane = tid & 15;

  // ---- rank phase: one preload round, then process ----
  uint32_t lenv[16];
  uint64_t pre[16];
#pragma unroll
  for (int s = 0; s < 16; ++s) {
    int seg = team + (s << 4);            // team, team+16, ..., team+240
    lenv[s] = (seg < NWG_A) ? s_len[seg] : 0u;
    pre[s] = (seg < NWG_A)
        ? __builtin_nontemporal_load(coarse + ((size_t)seg * NB + b) * CAPW + lane)
        : 0ull;
  }

#define RANK(p)                                                              \
  {                                                                          \
    uint32_t r = (uint32_t)((p) >> 48);                                      \
    uint32_t rl = r & (BROWS - 1);                                           \
    uint32_t idx = atomicAdd(&cnt[rl], 1u);                                  \
    if (idx < CAP) {                                                         \
      uint32_t c = (uint32_t)((p) >> 32) & 0xFFFFu;                          \
      pay[rl * CAP + ((idx + rl) & (CAP - 1))] = (c << 16) | f2bf((uint32_t)(p)); \
    } else {                                                                 \
      uint32_t oi = atomicAdd(&ovfc, 1u);                                    \
      if (oi < OVF_PB) ovfB[(size_t)b * OVF_PB + oi] = (p);                  \
    }                                                                        \
  }

#pragma unroll
  for (int s = 0; s < 16; ++s) {
    if ((uint32_t)lane < lenv[s]) RANK(pre[s]);
  }
  // rare tail: len > 16 (+3.2 sigma at mean 7.35; ~0.07% of segments)
#pragma unroll
  for (int s = 0; s < 16; ++s) {
    uint32_t len = lenv[s];
    if (len > 16u) {
      int seg = team + (s << 4);
      const uint64_t* cseg = coarse + ((size_t)seg * NB + b) * CAPW;
      for (uint32_t li = 16u + (uint32_t)lane; li < len; li += 16) {
        uint64_t p = __builtin_nontemporal_load(cseg + li);
        RANK(p);
      }
    }
  }
#undef RANK
  __syncthreads();
  if (tid == 0) ovfcB[b] = min(ovfc, (uint32_t)OVF_PB);

  // ---- gather phase ----
  const uint4* x4 = (const uint4*)xb;     // row stride: 16 uint4 (128 bf16)
  const int r0 = b << RSHIFT;

#define GSTEP(ww)                                                            \
  {                                                                          \
    uint32_t cc = (ww) >> 16;                                                \
    float vv = __uint_as_float((ww) << 16);                                  \
    uint4 a = x4[(size_t)cc * 16 + lane];                                    \
    acc0 += vv * __uint_as_float(a.x << 16);                                 \
    acc1 += vv * __uint_as_float(a.x & 0xffff0000u);                         \
    acc2 += vv * __uint_as_float(a.y << 16);                                 \
    acc3 += vv * __uint_as_float(a.y & 0xffff0000u);                         \
    acc4 += vv * __uint_as_float(a.z << 16);                                 \
    acc5 += vv * __uint_as_float(a.z & 0xffff0000u);                         \
    acc6 += vv * __uint_as_float(a.w << 16);                                 \
    acc7 += vv * __uint_as_float(a.w & 0xffff0000u);                         \
  }

  for (int rl = team; rl < BROWS; rl += 16) {
    int r = r0 + rl;
    if (r >= N_NODES) continue;
    uint32_t n = (min(cnt[rl], (uint32_t)CAP) + 7u) & ~7u;  // pads are zeros
    const uint32_t* prow = &pay[rl * CAP];
    float acc0 = 0.f, acc1 = 0.f, acc2 = 0.f, acc3 = 0.f;
    float acc4 = 0.f, acc5 = 0.f, acc6 = 0.f, acc7 = 0.f;
    for (uint32_t j = 0; j < n; j += 8) {
      // 8 wave-uniform LDS broadcast reads (rotated), 8 x-row loads in flight
      uint32_t w0 = prow[(j + 0 + rl) & (CAP - 1)];
      uint32_t w1 = prow[(j + 1 + rl) & (CAP - 1)];
      uint32_t w2 = prow[(j + 2 + rl) & (CAP - 1)];
      uint32_t w3 = prow[(j + 3 + rl) & (CAP - 1)];
      uint32_t w4 = prow[(j + 4 + rl) & (CAP - 1)];
      uint32_t w5 = prow[(j + 5 + rl) & (CAP - 1)];
      uint32_t w6 = prow[(j + 6 + rl) & (CAP - 1)];
      uint32_t w7 = prow[(j + 7 + rl) & (CAP - 1)];
      GSTEP(w0) GSTEP(w1) GSTEP(w2) GSTEP(w3)
      GSTEP(w4) GSTEP(w5) GSTEP(w6) GSTEP(w7)
    }
    f4v lo, hi;
    lo.x = acc0; lo.y = acc1; lo.z = acc2; lo.w = acc3;
    hi.x = acc4; hi.y = acc5; hi.z = acc6; hi.w = acc7;
    f4v* o = (f4v*)out + (size_t)r * 32 + lane * 2;
    __builtin_nontemporal_store(lo, o);
    __builtin_nontemporal_store(hi, o + 1);
  }
#undef GSTEP
}

// exact cleanup for packed (row,col,f32val) u64 overflow entries. Early-exits
// when all 1032 region counts are zero (the expected case).
__global__ void __launch_bounds__(256) ovf_pack_kernel(const float* __restrict__ x,
                                                       const uint32_t* __restrict__ ovfcA,
                                                       const uint64_t* __restrict__ ovfA,
                                                       const uint32_t* __restrict__ ovfcB,
                                                       const uint64_t* __restrict__ ovfB,
                                                       float* __restrict__ out) {
  __shared__ int any;
  if (threadIdx.x == 0) any = 0;
  __syncthreads();
  for (int t = threadIdx.x; t < NREG; t += 256) {
    uint32_t c = (t < NWG_A) ? ovfcA[t] : ovfcB[t - NWG_A];
    if (c) any = 1;
  }
  __syncthreads();
  if (!any) return;

  int group = (int)((blockIdx.x * 256 + threadIdx.x) >> 7);
  int f = threadIdx.x & 127;
  const int ngroups = (16 * 256) >> 7;  // 32 groups
  for (int reg = group; reg < NREG; reg += ngroups) {
    uint32_t c;
    const uint64_t* basep;
    if (reg < NWG_A) {
      c = min(ovfcA[reg], (uint32_t)OVF_PW);
      basep = ovfA + (size_t)reg * OVF_PW;
    } else {
      c = min(ovfcB[reg - NWG_A], (uint32_t)OVF_PB);
      basep = ovfB + (size_t)(reg - NWG_A) * OVF_PB;
    }
    for (uint32_t i = 0; i < c; ++i) {
      uint64_t p = basep[i];
      uint32_t r = (uint32_t)(p >> 48);
      uint32_t cc = (uint32_t)((p >> 32) & 0xFFFFu);
      float v = __uint_as_float((uint32_t)p);
      atomicAdd(&out[(size_t)r * N_FEAT + f], v * x[(size_t)cc * N_FEAT + f]);
    }
  }
}

// =================== FALLBACK: fused atomic scatter ============================

__global__ void __launch_bounds__(256) scatter_fused_kernel(const float* __restrict__ x,
                                                            const float* __restrict__ adj_vals,
                                                            const int* __restrict__ row,
                                                            const int* __restrict__ col,
                                                            float* __restrict__ out) {
  long long t = (long long)blockIdx.x * blockDim.x + threadIdx.x;
  int e = (int)(t >> 6);
  int lane = (int)(t & 63);
  if (e >= N_EDGES) return;
  if (!edge_keep((uint32_t)e)) return;
  float v = adj_vals[e] / 0.9f;
  float2 xf = *(const float2*)(x + (long long)col[e] * N_FEAT + lane * 2);
  float* dst = out + (long long)row[e] * N_FEAT + lane * 2;
  atomicAdd(dst, v * xf.x);
  atomicAdd(dst + 1, v * xf.y);
}

// ---------------- launch --------------------------------------------------------

extern "C" void kernel_launch(void* const* d_in, const int* in_sizes, int n_in,
                              void* d_out, int out_size, void* d_ws, size_t ws_size,
                              hipStream_t stream) {
  const float* x        = (const float*)d_in[0];
  const float* adj_vals = (const float*)d_in[1];
  const int*   row      = (const int*)d_in[2];
  const int*   col      = (const int*)d_in[3];
  float* out = (float*)d_out;

  // ---- workspace layout (nothing needs host-side init) ----
  size_t a_ovfcA   = 0;                                                    // NWG_A u32
  size_t a_ovfcB   = (a_ovfcA + (size_t)NWG_A * 4 + 255) & ~255ull;        // NB u32
  size_t a_lens    = (a_ovfcB + (size_t)NB * 4 + 255) & ~255ull;           // NB*NWG_A u32
  size_t a_ovfA    = (a_lens + (size_t)NB * NWG_A * 4 + 255) & ~255ull;    // NWG_A*OVF_PW u64
  size_t a_ovfB    = (a_ovfA + (size_t)NWG_A * OVF_PW * 8 + 255) & ~255ull; // NB*OVF_PB u64
  size_t a_coarse  = (a_ovfB + (size_t)NB * OVF_PB * 8 + 255) & ~255ull;   // NWG_A*NB*CAPW u64
  size_t a_xb      = (a_coarse + (size_t)NWG_A * NB * CAPW * 8 + 255) & ~255ull;  // N*F bf16
  size_t need      = a_xb + (size_t)N_NODES * N_FEAT * 2;

  if (ws_size >= need) {
    uint32_t* ovfcA = (uint32_t*)((char*)d_ws + a_ovfcA);
    uint32_t* ovfcB = (uint32_t*)((char*)d_ws + a_ovfcB);
    uint32_t* lens  = (uint32_t*)((char*)d_ws + a_lens);
    uint64_t* ovfA  = (uint64_t*)((char*)d_ws + a_ovfA);
    uint64_t* ovfB  = (uint64_t*)((char*)d_ws + a_ovfB);
    uint64_t* coarse = (uint64_t*)((char*)d_ws + a_coarse);
    uint32_t* xb    = (uint32_t*)((char*)d_ws + a_xb);

    convA_kernel<<<NWG_A, A_THREADS, 0, stream>>>(x, xb, adj_vals, row, col,
                                                  coarse, lens, ovfcA, ovfA);
    rank_gather_kernel<<<NB, 256, 0, stream>>>(xb, coarse, lens, ovfcB, ovfB, out);
    ovf_pack_kernel<<<16, 256, 0, stream>>>(x, ovfcA, ovfA, ovfcB, ovfB, out);
  } else {
    hipMemsetAsync(d_out, 0, (size_t)out_size * sizeof(float), stream);
    long long total_threads = (long long)N_EDGES * 64;
    scatter_fused_kernel<<<(int)((total_threads + 255) / 256), 256, 0, stream>>>(
        x, adj_vals, row, col, out);
  }
}

// Round 13
// 153.420 us; speedup vs baseline: 1.0539x; 1.0539x over previous
//
#include <hip/hip_runtime.h>
#include <stdint.h>

#define N_NODES 50000
#define N_EDGES 1600000
#define N_FEAT 128
#define CAP 64            // final slots per row; Poisson(28.8) mean, +6.5 sigma
#define OVF_PW 256        // per-convA-wg overflow slots (expected usage: ~0)
#define OVF_PB 192        // per-bucket overflow slots (expected usage: ~0)

// radix-partition parameters (round-10 best-measured geometry: 152.1us)
#define RSHIFT 7          // 128 rows per bucket: NB=391 fills all CUs
#define BROWS 128
#define NB 391            // ceil(50000 / 128)
#define NWG_A 250         // pass-A workgroups; 250*1600 chunks * 4 edges = 1.6M exact
#define A_THREADS 1024
#define CHUNKS_PW 1600    // 4-edge chunks per pass-A wg
#define CAPW 40           // slots per (bucket, wg) segment; mean 14.7, +6.6 sigma
#define NREG (NWG_A + NB) // 641 overflow regions total

// ---------------- threefry2x32 (bit-exact, KAT-verified vs Random123) ----------

struct KeyPair { uint32_t a, b; };

__host__ __device__ constexpr inline uint32_t rotl32(uint32_t x, int r) {
  return (x << r) | (x >> (32 - r));
}

__host__ __device__ constexpr inline KeyPair threefry2x32(uint32_t k0, uint32_t k1,
                                                          uint32_t x0, uint32_t x1) {
  const uint32_t ks0 = k0, ks1 = k1, ks2 = k0 ^ k1 ^ 0x1BD11BDAu;
  x0 += ks0;
  x1 += ks1;
  const int rotA[4] = {13, 15, 26, 6};
  const int rotB[4] = {17, 29, 16, 24};
  const uint32_t ks[3] = {ks0, ks1, ks2};
  for (int i = 0; i < 5; ++i) {
    const int* rot = (i & 1) ? rotB : rotA;
    for (int j = 0; j < 4; ++j) {
      x0 += x1;
      x1 = rotl32(x1, rot[j]);
      x1 ^= x0;
    }
    x0 += ks[(i + 1) % 3];
    x1 += ks[(i + 2) % 3] + (uint32_t)(i + 1);
  }
  return {x0, x1};
}

// mask_key = fold_in(key(42), 7); compile-time.
constexpr KeyPair MASK_KEY = threefry2x32(0u, 42u, 0u, 7u);

// Partitionable (counter-mode) random_bits: element i -> threefry(key, (0, i)), bits = b1^b2.
__device__ inline bool edge_keep(uint32_t e) {
  KeyPair r = threefry2x32(MASK_KEY.a, MASK_KEY.b, 0u, e);
  uint32_t bits = r.a ^ r.b;
  float u = __uint_as_float((bits >> 9) | 0x3f800000u) - 1.0f;
  return u < 0.9f;
}

// fp32 bits -> bf16 with round-to-nearest-even
__device__ inline uint32_t f2bf(uint32_t b) {
  return (b + 0x7fffu + ((b >> 16) & 1u)) >> 16;
}

// true vector types (ext_vector_type) -- __builtin_nontemporal_* rejects HIP's
// class-type uint2/float4, but accepts these (identical layout & codegen).
typedef uint32_t u4v __attribute__((ext_vector_type(4)));
typedef int32_t  i4v __attribute__((ext_vector_type(4)));
typedef float    f4v __attribute__((ext_vector_type(4)));

// =================== PRIMARY PATH ==============================================
// coarse pack (8B u64): (row << 48) | (col << 32) | f32bits(val).
// coarse layout (round 13): BUCKET-major -- coarse[(b*NWG_A + seg)*CAPW + li].
// r8 measured the WRITER indifferent to layout (wg-major vs bucket-major:
// neutral); the READER (rank phase) is not: bucket-major makes each rank wg's
// whole read footprint one contiguous 80KB window (250 adjacent segments)
// instead of 250 islands strided 125KB across 31MB.
// Post-mortems baked in: no global atomics (r2), cached producer->consumer
// stores / NT for read-once streams (r4), eager preloads (r5), fused conversion
// (r7), LDS payload in merged rank+gather (r9, -8us), rank preload rounds (r10,
// -4us), +rl pay swizzle (r11, conflict fix, free). REVERTED: 5B coarse split
// (r11, +6us), 64-row buckets (r12, +6us: over-read + per-bucket overhead up,
// occupancy unchanged).

// Pass A (fused with x->bf16 conversion): per-wg compaction into (bucket, wg)
// segments using LDS counters only. One barrier, before phase 0. Edge arrays +
// x read-once -> NT loads. Per-wg overflow count written unconditionally.
__global__ void __launch_bounds__(A_THREADS) convA_kernel(const float* __restrict__ x,
                                                          uint32_t* __restrict__ xb,
                                                          const float* __restrict__ adj_vals,
                                                          const int* __restrict__ row,
                                                          const int* __restrict__ col,
                                                          uint64_t* __restrict__ coarse,
                                                          uint32_t* __restrict__ lens,
                                                          uint32_t* __restrict__ ovfcA,
                                                          uint64_t* __restrict__ ovfA) {
  __shared__ uint32_t cnt[NB];
  __shared__ uint32_t ovfc;
  int wg = blockIdx.x;
  int tid = threadIdx.x;
  if (tid < NB) cnt[tid] = 0;
  if (tid == 0) ovfc = 0;
  __syncthreads();  // cnt/ovfc init visible to phase-1 atomics (only barrier)

  // phase 0: x -> bf16, 32B in / 16B out per iteration (NT in, cached out)
  const int gthreads = NWG_A * A_THREADS;
  for (int i = wg * A_THREADS + tid; i < (N_NODES * N_FEAT) / 8; i += gthreads) {
    f4v a = __builtin_nontemporal_load((const f4v*)x + 2 * i);
    f4v b = __builtin_nontemporal_load((const f4v*)x + 2 * i + 1);
    u4v o;
    o.x = f2bf(__float_as_uint(a.x)) | (f2bf(__float_as_uint(a.y)) << 16);
    o.y = f2bf(__float_as_uint(a.z)) | (f2bf(__float_as_uint(a.w)) << 16);
    o.z = f2bf(__float_as_uint(b.x)) | (f2bf(__float_as_uint(b.y)) << 16);
    o.w = f2bf(__float_as_uint(b.z)) | (f2bf(__float_as_uint(b.w)) << 16);
    ((u4v*)xb)[i] = o;
  }

  // phase 1: bin 4-edge chunks (NT vector loads), LDS-atomic slot ranks,
  // bucket-major coarse scatter
  for (int ch = tid; ch < CHUNKS_PW; ch += A_THREADS) {
    const int g = wg * CHUNKS_PW + ch;     // global chunk; edges [4g, 4g+4)
    const i4v r4 = __builtin_nontemporal_load((const i4v*)row + g);
    const i4v c4 = __builtin_nontemporal_load((const i4v*)col + g);
    const f4v a4 = __builtin_nontemporal_load((const f4v*)adj_vals + g);
    const int rr[4] = {r4.x, r4.y, r4.z, r4.w};
    const int cc[4] = {c4.x, c4.y, c4.z, c4.w};
    const float aa[4] = {a4.x, a4.y, a4.z, a4.w};
#pragma unroll
    for (int k = 0; k < 4; ++k) {
      const uint32_t e = (uint32_t)(4 * g + k);
      if (!edge_keep(e)) continue;
      const uint32_t r = (uint32_t)rr[k];
      const uint32_t c = (uint32_t)cc[k];
      const float v = aa[k] / 0.9f;
      const uint32_t b = r >> RSHIFT;
      const uint32_t li = atomicAdd(&cnt[b], 1u);
      const uint64_t p = ((uint64_t)r << 48) | ((uint64_t)c << 32) | (uint64_t)__float_as_uint(v);
      if (li < CAPW) {
        coarse[((size_t)b * NWG_A + wg) * CAPW + li] = p;
      } else {
        const uint32_t oi = atomicAdd(&ovfc, 1u);
        if (oi < OVF_PW) ovfA[(size_t)wg * OVF_PW + oi] = p;
      }
    }
  }
  __syncthreads();
  if (tid < NB) lens[(size_t)tid * NWG_A + wg] = min(cnt[tid], (uint32_t)CAPW);
  if (tid == 0) ovfcA[wg] = min(ovfc, (uint32_t)OVF_PW);
}

// Merged rank + gather: one 512-thread wg per 128-row bucket (r10 geometry).
// Rank: two preload rounds (first-16 unconditional, 16..31 conditional -- 8+8
// independent NT loads in flight), then process; rare len>32 tail. Bucket-major
// coarse: this wg's 250 segments are CONTIGUOUS (80KB window). +rl pay swizzle
// (bank = (idx+rl)&31, r11).
__global__ void __launch_bounds__(512) rank_gather_kernel(const uint32_t* __restrict__ xb,
                                                          const uint64_t* __restrict__ coarse,
                                                          const uint32_t* __restrict__ lens,
                                                          uint32_t* __restrict__ ovfcB,
                                                          uint64_t* __restrict__ ovfB,
                                                          float* __restrict__ out) {
  int b = blockIdx.x;
  int tid = threadIdx.x;
  __shared__ uint32_t pay[BROWS * CAP];   // 32 KB payload tile
  __shared__ uint32_t cnt[BROWS];
  __shared__ uint32_t s_len[NWG_A];
  __shared__ uint32_t ovfc;
  for (int i = tid; i < BROWS * CAP; i += 512) pay[i] = 0u;
  if (tid < BROWS) cnt[tid] = 0;
  if (tid < NWG_A) s_len[tid] = lens[(size_t)b * NWG_A + tid];
  if (tid == 0) ovfc = 0;
  __syncthreads();

  int team = tid >> 4;        // 32 teams of 16 lanes
  int lane = tid & 15;
  const uint64_t* cbase = coarse + (size_t)b * NWG_A * CAPW;  // contiguous 80KB

  // ---- rank phase: preload rounds, then process ----
  uint32_t lenv[8];
  uint64_t pre[8];
#pragma unroll
  for (int s8 = 0; s8 < 8; ++s8) {
    int seg = team + (s8 << 5);
    lenv[s8] = (seg < NWG_A) ? s_len[seg] : 0u;
    pre[s8] = (seg < NWG_A)
        ? __builtin_nontemporal_load(cbase + (size_t)seg * CAPW + lane)
        : 0ull;
  }
  uint64_t tl[8];
#pragma unroll
  for (int s8 = 0; s8 < 8; ++s8) {
    int seg = team + (s8 << 5);
    bool tv = (lenv[s8] > 16u && (uint32_t)(lane + 16) < lenv[s8]);
    tl[s8] = tv ? __builtin_nontemporal_load(cbase + (size_t)seg * CAPW + 16 + lane) : 0ull;
  }

#define RANK(p)                                                              \
  {                                                                          \
    uint32_t r = (uint32_t)((p) >> 48);                                      \
    uint32_t rl = r & (BROWS - 1);                                           \
    uint32_t idx = atomicAdd(&cnt[rl], 1u);                                  \
    if (idx < CAP) {                                                         \
      uint32_t c = (uint32_t)((p) >> 32) & 0xFFFFu;                          \
      pay[rl * CAP + ((idx + rl) & (CAP - 1))] = (c << 16) | f2bf((uint32_t)(p)); \
    } else {                                                                 \
      uint32_t oi = atomicAdd(&ovfc, 1u);                                    \
      if (oi < OVF_PB) ovfB[(size_t)b * OVF_PB + oi] = (p);                  \
    }                                                                        \
  }

#pragma unroll
  for (int s8 = 0; s8 < 8; ++s8) {
    if ((uint32_t)lane < lenv[s8]) RANK(pre[s8]);
  }
#pragma unroll
  for (int s8 = 0; s8 < 8; ++s8) {
    if (lenv[s8] > 16u && (uint32_t)(lane + 16) < lenv[s8]) RANK(tl[s8]);
  }
  // rare tail: len > 32 (+4.5 sigma at mean 14.7)
#pragma unroll
  for (int s8 = 0; s8 < 8; ++s8) {
    uint32_t len = lenv[s8];
    if (len > 32u) {
      int seg = team + (s8 << 5);
      const uint64_t* cseg = cbase + (size_t)seg * CAPW;
      for (uint32_t li = 32u + (uint32_t)lane; li < len; li += 16) {
        uint64_t p = __builtin_nontemporal_load(cseg + li);
        RANK(p);
      }
    }
  }
#undef RANK
  __syncthreads();
  if (tid == 0) ovfcB[b] = min(ovfc, (uint32_t)OVF_PB);

  // ---- gather phase ----
  const uint4* x4 = (const uint4*)xb;     // row stride: 16 uint4 (128 bf16)
  const int r0 = b << RSHIFT;

#define GSTEP(ww)                                                            \
  {                                                                          \
    uint32_t cc = (ww) >> 16;                                                \
    float vv = __uint_as_float((ww) << 16);                                  \
    uint4 a = x4[(size_t)cc * 16 + lane];                                    \
    acc0 += vv * __uint_as_float(a.x << 16);                                 \
    acc1 += vv * __uint_as_float(a.x & 0xffff0000u);                         \
    acc2 += vv * __uint_as_float(a.y << 16);                                 \
    acc3 += vv * __uint_as_float(a.y & 0xffff0000u);                         \
    acc4 += vv * __uint_as_float(a.z << 16);                                 \
    acc5 += vv * __uint_as_float(a.z & 0xffff0000u);                         \
    acc6 += vv * __uint_as_float(a.w << 16);                                 \
    acc7 += vv * __uint_as_float(a.w & 0xffff0000u);                         \
  }

  for (int rl = team; rl < BROWS; rl += 32) {
    int r = r0 + rl;
    if (r >= N_NODES) continue;
    uint32_t n = (min(cnt[rl], (uint32_t)CAP) + 7u) & ~7u;  // pads are zeros
    const uint32_t* prow = &pay[rl * CAP];
    float acc0 = 0.f, acc1 = 0.f, acc2 = 0.f, acc3 = 0.f;
    float acc4 = 0.f, acc5 = 0.f, acc6 = 0.f, acc7 = 0.f;
    for (uint32_t j = 0; j < n; j += 8) {
      // 8 wave-uniform LDS broadcast reads (rotated), 8 x-row loads in flight
      uint32_t w0 = prow[(j + 0 + rl) & (CAP - 1)];
      uint32_t w1 = prow[(j + 1 + rl) & (CAP - 1)];
      uint32_t w2 = prow[(j + 2 + rl) & (CAP - 1)];
      uint32_t w3 = prow[(j + 3 + rl) & (CAP - 1)];
      uint32_t w4 = prow[(j + 4 + rl) & (CAP - 1)];
      uint32_t w5 = prow[(j + 5 + rl) & (CAP - 1)];
      uint32_t w6 = prow[(j + 6 + rl) & (CAP - 1)];
      uint32_t w7 = prow[(j + 7 + rl) & (CAP - 1)];
      GSTEP(w0) GSTEP(w1) GSTEP(w2) GSTEP(w3)
      GSTEP(w4) GSTEP(w5) GSTEP(w6) GSTEP(w7)
    }
    f4v lo, hi;
    lo.x = acc0; lo.y = acc1; lo.z = acc2; lo.w = acc3;
    hi.x = acc4; hi.y = acc5; hi.z = acc6; hi.w = acc7;
    f4v* o = (f4v*)out + (size_t)r * 32 + lane * 2;
    __builtin_nontemporal_store(lo, o);
    __builtin_nontemporal_store(hi, o + 1);
  }
#undef GSTEP
}

// exact cleanup for packed (row,col,f32val) u64 overflow entries. Early-exits
// when all region counts are zero (the expected case).
__global__ void __launch_bounds__(256) ovf_pack_kernel(const float* __restrict__ x,
                                                       const uint32_t* __restrict__ ovfcA,
                                                       const uint64_t* __restrict__ ovfA,
                                                       const uint32_t* __restrict__ ovfcB,
                                                       const uint64_t* __restrict__ ovfB,
                                                       float* __restrict__ out) {
  __shared__ int any;
  if (threadIdx.x == 0) any = 0;
  __syncthreads();
  for (int t = threadIdx.x; t < NREG; t += 256) {
    uint32_t c = (t < NWG_A) ? ovfcA[t] : ovfcB[t - NWG_A];
    if (c) any = 1;
  }
  __syncthreads();
  if (!any) return;

  int group = (int)((blockIdx.x * 256 + threadIdx.x) >> 7);
  int f = threadIdx.x & 127;
  const int ngroups = (16 * 256) >> 7;  // 32 groups
  for (int reg = group; reg < NREG; reg += ngroups) {
    uint32_t c;
    const uint64_t* basep;
    if (reg < NWG_A) {
      c = min(ovfcA[reg], (uint32_t)OVF_PW);
      basep = ovfA + (size_t)reg * OVF_PW;
    } else {
      c = min(ovfcB[reg - NWG_A], (uint32_t)OVF_PB);
      basep = ovfB + (size_t)(reg - NWG_A) * OVF_PB;
    }
    for (uint32_t i = 0; i < c; ++i) {
      uint64_t p = basep[i];
      uint32_t r = (uint32_t)(p >> 48);
      uint32_t cc = (uint32_t)((p >> 32) & 0xFFFFu);
      float v = __uint_as_float((uint32_t)p);
      atomicAdd(&out[(size_t)r * N_FEAT + f], v * x[(size_t)cc * N_FEAT + f]);
    }
  }
}

// =================== FALLBACK: fused atomic scatter ============================

__global__ void __launch_bounds__(256) scatter_fused_kernel(const float* __restrict__ x,
                                                            const float* __restrict__ adj_vals,
                                                            const int* __restrict__ row,
                                                            const int* __restrict__ col,
                                                            float* __restrict__ out) {
  long long t = (long long)blockIdx.x * blockDim.x + threadIdx.x;
  int e = (int)(t >> 6);
  int lane = (int)(t & 63);
  if (e >= N_EDGES) return;
  if (!edge_keep((uint32_t)e)) return;
  float v = adj_vals[e] / 0.9f;
  float2 xf = *(const float2*)(x + (long long)col[e] * N_FEAT + lane * 2);
  float* dst = out + (long long)row[e] * N_FEAT + lane * 2;
  atomicAdd(dst, v * xf.x);
  atomicAdd(dst + 1, v * xf.y);
}

// ---------------- launch --------------------------------------------------------

extern "C" void kernel_launch(void* const* d_in, const int* in_sizes, int n_in,
                              void* d_out, int out_size, void* d_ws, size_t ws_size,
                              hipStream_t stream) {
  const float* x        = (const float*)d_in[0];
  const float* adj_vals = (const float*)d_in[1];
  const int*   row      = (const int*)d_in[2];
  const int*   col      = (const int*)d_in[3];
  float* out = (float*)d_out;

  // ---- workspace layout (nothing needs host-side init) ----
  size_t a_ovfcA   = 0;                                                    // NWG_A u32
  size_t a_ovfcB   = (a_ovfcA + (size_t)NWG_A * 4 + 255) & ~255ull;        // NB u32
  size_t a_lens    = (a_ovfcB + (size_t)NB * 4 + 255) & ~255ull;           // NB*NWG_A u32
  size_t a_ovfA    = (a_lens + (size_t)NB * NWG_A * 4 + 255) & ~255ull;    // NWG_A*OVF_PW u64
  size_t a_ovfB    = (a_ovfA + (size_t)NWG_A * OVF_PW * 8 + 255) & ~255ull; // NB*OVF_PB u64
  size_t a_coarse  = (a_ovfB + (size_t)NB * OVF_PB * 8 + 255) & ~255ull;   // NB*NWG_A*CAPW u64
  size_t a_xb      = (a_coarse + (size_t)NB * NWG_A * CAPW * 8 + 255) & ~255ull;  // N*F bf16
  size_t need      = a_xb + (size_t)N_NODES * N_FEAT * 2;

  if (ws_size >= need) {
    uint32_t* ovfcA = (uint32_t*)((char*)d_ws + a_ovfcA);
    uint32_t* ovfcB = (uint32_t*)((char*)d_ws + a_ovfcB);
    uint32_t* lens  = (uint32_t*)((char*)d_ws + a_lens);
    uint64_t* ovfA  = (uint64_t*)((char*)d_ws + a_ovfA);
    uint64_t* ovfB  = (uint64_t*)((char*)d_ws + a_ovfB);
    uint64_t* coarse = (uint64_t*)((char*)d_ws + a_coarse);
    uint32_t* xb    = (uint32_t*)((char*)d_ws + a_xb);

    convA_kernel<<<NWG_A, A_THREADS, 0, stream>>>(x, xb, adj_vals, row, col,
                                                  coarse, lens, ovfcA, ovfA);
    rank_gather_kernel<<<NB, 512, 0, stream>>>(xb, coarse, lens, ovfcB, ovfB, out);
    ovf_pack_kernel<<<16, 256, 0, stream>>>(x, ovfcA, ovfA, ovfcB, ovfB, out);
  } else {
    hipMemsetAsync(d_out, 0, (size_t)out_size * sizeof(float), stream);
    long long total_threads = (long long)N_EDGES * 64;
    scatter_fused_kernel<<<(int)((total_threads + 255) / 256), 256, 0, stream>>>(
        x, adj_vals, row, col, out);
  }
}